// Round 5
// baseline (138.814 us; speedup 1.0000x reference)
//
#include <hip/hip_runtime.h>
#include <hip/hip_bf16.h>

using short8  = __attribute__((ext_vector_type(8))) short;
using floatx4 = __attribute__((ext_vector_type(4))) float;

// ---------------------------------------------------------------------------
// prepack: weights fp32 -> bf16 in MFMA-B-fragment-tiled layout (verified R4).
// Fragment (nblk, kstep) = 64 lanes x 8 elems contiguous; lane l holds
// B[n = nblk*16 + (l&15)][k = kstep*32 + (l>>4)*8 .. +7].
//  wsb_t: w_sample [256 s][1024 k] -> 16 nblk x 32 kstep
//  wib_t: w_init  [1024 k'][256 s] -> 64 nblk x  8 kstep
// ---------------------------------------------------------------------------
__global__ __launch_bounds__(256) void prepack_kernel(const float* __restrict__ w_sample,
                                                      const float* __restrict__ w_init,
                                                      __hip_bfloat16* __restrict__ wsb_t,
                                                      __hip_bfloat16* __restrict__ wib_t) {
    const int tg   = blockIdx.x * 256 + threadIdx.x;   // 0..65535
    const int lane = tg & 63;
    const int l16  = lane & 15, quad = lane >> 4;
    const float* src;
    __hip_bfloat16* dst;
    if (tg < 32768) {
        const int chunk = tg >> 6;                     // nblk=chunk>>5, kstep=chunk&31
        const int n = (chunk >> 5) * 16 + l16;
        const int k = (chunk & 31) * 32 + quad * 8;
        src = w_sample + (size_t)n * 1024 + k;
        dst = wsb_t + (size_t)tg * 8;
    } else {
        const int t2 = tg - 32768;
        const int chunk = t2 >> 6;                     // nblk=chunk>>3, kstep=chunk&7
        const int n = (chunk >> 3) * 16 + l16;
        const int k = (chunk & 7) * 32 + quad * 8;
        src = w_init + (size_t)n * 256 + k;
        dst = wib_t + (size_t)t2 * 8;
    }
    floatx4 v0 = *(const floatx4*)(src);
    floatx4 v1 = *(const floatx4*)(src + 4);
    union { short8 s; __hip_bfloat16 h[8]; } u;
#pragma unroll
    for (int i = 0; i < 4; ++i) {
        u.h[i]     = __float2bfloat16(v0[i]);
        u.h[4 + i] = __float2bfloat16(v1[i]);
    }
    *(short8*)dst = u.s;
}

// ---------------------------------------------------------------------------
// fused (R5): 512 threads = 8 waves; block = 32 patches (one (b,nh) slab).
// Grid 512 -> 2 blocks/CU = 16 waves/CU = 4 waves/SIMD.
//  Phase 1: meas[32x256] = patch[32x1024] @ Ws^T. BK=128, 8 iters, As
//    ping-pong [32][136] (pad 8: frag-read stride 272 B -> 2-way = free),
//    ONE barrier/iter; wave n-tile 32 (8 waves cover 256 once — same weight
//    L2 traffic as R4); B-frags register-direct from wsb_t, issued at iter
//    top so L2 latency hides under cvt+barrier.
//  Ms [32][264] (padded). Phase 2 barrier-free: each wave 128 of 1024 cols,
//    2 chunks x (2x4 MFMA x 8 ks); B-frags register-direct from wib_t;
//    fold epilogue straight to y fp32.
// Layouts (verified): A/B frag row=lane&15, k=quad*8+j; C/D col=lane&15,
// row=quad*4+reg.
// ---------------------------------------------------------------------------
__global__ __launch_bounds__(512, 2) void fused_kernel(const float* __restrict__ x,
                                                       const __hip_bfloat16* __restrict__ wsb_t,
                                                       const __hip_bfloat16* __restrict__ wib_t,
                                                       float* __restrict__ Y) {
    __shared__ __hip_bfloat16 As[2][32 * 136];   // ping-pong A tile, stride 136
    __shared__ __hip_bfloat16 Ms[32 * 264];      // meas tile, stride 264

    const int tid  = threadIdx.x;
    const int wave = tid >> 6, lane = tid & 63;
    const int quad = lane >> 4, l16 = lane & 15;
    const int blk  = blockIdx.x;                 // blk = b*32 + nh

    // A staging: thread -> (row arow = nw, 8 consecutive k at ak8)
    const int arow = tid >> 4;                   // 0..31
    const int ak8  = (tid & 15) * 8;             // 0..120, stays within a kh row
    const int akh  = ak8 >> 5, akw = ak8 & 31;
    const float* srcX = x + (size_t)blk * 32768 + (size_t)akh * 1024 + arow * 32 + akw;
    __hip_bfloat16* dstA0 = &As[0][arow * 136 + ak8];
    __hip_bfloat16* dstA1 = &As[1][arow * 136 + ak8];

    const __hip_bfloat16* baseW1 = wsb_t + lane * 8;
    const __hip_bfloat16* baseW2 = wib_t + lane * 8;

    floatx4 acc[2][2];
#pragma unroll
    for (int i = 0; i < 2; ++i)
#pragma unroll
        for (int j = 0; j < 2; ++j) acc[i][j] = {0.f, 0.f, 0.f, 0.f};

    // ---------------- phase 1 ----------------
    floatx4 v0 = *(const floatx4*)(srcX);
    floatx4 v1 = *(const floatx4*)(srcX + 4);
    srcX += 4096;                                // +128 k = +4 image rows

    for (int it = 0; it < 8; ++it) {
        // B-frags for this iter (register-direct; hide L2 latency under
        // the cvt + barrier below). nblk = wave*2+j, kstep = it*4+kk.
        short8 bfr[4][2];
#pragma unroll
        for (int kk = 0; kk < 4; ++kk)
#pragma unroll
            for (int j = 0; j < 2; ++j)
                bfr[kk][j] = *(const short8*)(baseW1 +
                    (size_t)((wave * 2 + j) * 32 + it * 4 + kk) * 512);

        union { short8 s; __hip_bfloat16 h[8]; } u;
#pragma unroll
        for (int q = 0; q < 4; ++q) {
            u.h[q]     = __float2bfloat16(v0[q]);
            u.h[4 + q] = __float2bfloat16(v1[q]);
        }
        *(short8*)((it & 1) ? dstA1 : dstA0) = u.s;
        __syncthreads();
        if (it < 7) {                            // prefetch next slab chunk
            v0 = *(const floatx4*)(srcX);
            v1 = *(const floatx4*)(srcX + 4);
            srcX += 4096;
        }
        const __hip_bfloat16* Ap = As[it & 1];
#pragma unroll
        for (int kk = 0; kk < 4; ++kk) {
            short8 af[2];
#pragma unroll
            for (int i = 0; i < 2; ++i)
                af[i] = *(const short8*)&Ap[(i * 16 + l16) * 136 + kk * 32 + quad * 8];
#pragma unroll
            for (int i = 0; i < 2; ++i)
#pragma unroll
                for (int j = 0; j < 2; ++j)
                    acc[i][j] = __builtin_amdgcn_mfma_f32_16x16x32_bf16(af[i], bfr[kk][j], acc[i][j], 0, 0, 0);
        }
    }

    // meas (C-layout) -> Ms row-major [m][s], cols n0 = wave*32
#pragma unroll
    for (int i = 0; i < 2; ++i)
#pragma unroll
        for (int r = 0; r < 4; ++r) {
            const int row = i * 16 + quad * 4 + r;
#pragma unroll
            for (int j = 0; j < 2; ++j)
                Ms[row * 264 + wave * 32 + j * 16 + l16] = __float2bfloat16(acc[i][j][r]);
        }
    __syncthreads();

    // ---------------- phase 2 (barrier-free) ----------------
    float* ybase = Y + (size_t)blk * 32768;
#pragma unroll 1
    for (int c2 = 0; c2 < 2; ++c2) {
        floatx4 a2[2][4];
#pragma unroll
        for (int i = 0; i < 2; ++i)
#pragma unroll
            for (int j = 0; j < 4; ++j) a2[i][j] = {0.f, 0.f, 0.f, 0.f};
#pragma unroll
        for (int ks = 0; ks < 8; ++ks) {
            short8 af[2], bfr[4];
#pragma unroll
            for (int i = 0; i < 2; ++i)
                af[i] = *(const short8*)&Ms[(i * 16 + l16) * 264 + ks * 32 + quad * 8];
#pragma unroll
            for (int j = 0; j < 4; ++j)
                bfr[j] = *(const short8*)(baseW2 +
                    (size_t)((wave * 8 + c2 * 4 + j) * 8 + ks) * 512);
#pragma unroll
            for (int i = 0; i < 2; ++i)
#pragma unroll
                for (int j = 0; j < 4; ++j)
                    a2[i][j] = __builtin_amdgcn_mfma_f32_16x16x32_bf16(af[i], bfr[j], a2[i][j], 0, 0, 0);
        }
        // fold epilogue: m = nw; col = wave*128 + c2*64 + j*16 + l16
#pragma unroll
        for (int i = 0; i < 2; ++i)
#pragma unroll
            for (int r = 0; r < 4; ++r) {
                const int m = i * 16 + quad * 4 + r;
#pragma unroll
                for (int j = 0; j < 4; ++j) {
                    const int col = wave * 128 + c2 * 64 + j * 16 + l16;
                    const int kh = col >> 5, kw = col & 31;
                    ybase[kh * 1024 + m * 32 + kw] = a2[i][j][r];
                }
            }
    }
}

// ---------------------------------------------------------------------------
// Workspace: wsb_t bf16 [262144] @ 0; wib_t bf16 [262144] @ 524288. 1 MB.
// ---------------------------------------------------------------------------
extern "C" void kernel_launch(void* const* d_in, const int* in_sizes, int n_in,
                              void* d_out, int out_size, void* d_ws, size_t ws_size,
                              hipStream_t stream) {
    const float* x        = (const float*)d_in[0];
    const float* w_sample = (const float*)d_in[1];
    const float* w_init   = (const float*)d_in[2];
    float* y = (float*)d_out;
    char* ws = (char*)d_ws;

    __hip_bfloat16* wsb_t = (__hip_bfloat16*)(ws);
    __hip_bfloat16* wib_t = (__hip_bfloat16*)(ws + (size_t)524288);

    prepack_kernel<<<256, 256, 0, stream>>>(w_sample, w_init, wsb_t, wib_t);
    fused_kernel<<<512, 512, 0, stream>>>(x, wsb_t, wib_t, y);
}